// Round 7
// baseline (291.596 us; speedup 1.0000x reference)
//
#include <hip/hip_runtime.h>
#include <hip/hip_cooperative_groups.h>
#include <math.h>

// Geometry (fixed): x (T=32, B=8, C=64, H=64, W=64) fp32 contiguous.
// SLICE = 262144 floats per (t,b) slice; 256 slices = 256 MiB total.
//
// Single cooperative kernel: 256 blocks x 512 threads (1 block/CU — this
// launch shape is VALIDATED to co-reside & grid-sync; R6's 512-block shape
// was rejected by the coop-launch occupancy check).
// Block bid owns slice bid. Per thread: 128 f32x4 chunks:
//   chunks  0..63  -> packed bf16 in 32 NAMED u32x4 vars (exactly 128 VGPRs;
//                     named scalars cannot be demoted to scratch like an array)
//   chunks 64..78  -> packed bf16 in LDS (61.4 KiB)
//   chunks 79..127 -> re-read from HBM in phase 3 (98 MiB total; read LAST in
//                     phase 1 and re-read FIRST in phase 3 -> good L3 odds)
// Sums computed from fp32 BEFORE bf16 pack. bf16 RNE err <= |x|*2^-9 << 5.4e-2.
#define TBCNT 256
#define SLICE 262144
#define THREADS 512
#define K_TOTAL 128
#define K_REGC 64
#define K_LDS 15

typedef float    f32x4 __attribute__((ext_vector_type(4)));
typedef unsigned u32x4 __attribute__((ext_vector_type(4)));

__device__ __forceinline__ unsigned pack2(float a, float b) {
    // RNE bf16 pack: a -> low 16, b -> high 16
    unsigned ua = __float_as_uint(a), ub = __float_as_uint(b);
    ua = (ua + 0x7FFFu + ((ua >> 16) & 1u)) >> 16;
    ub = (ub + 0x7FFFu + ((ub >> 16) & 1u)) & 0xFFFF0000u;
    return ua | ub;
}

__device__ __forceinline__ f32x4 unpack4(unsigned lo, unsigned hi, float s) {
    f32x4 v;
    v.x = __uint_as_float(lo << 16) * s;
    v.y = __uint_as_float(lo & 0xFFFF0000u) * s;
    v.z = __uint_as_float(hi << 16) * s;
    v.w = __uint_as_float(hi & 0xFFFF0000u) * s;
    return v;
}

#define SUM4(v) (((v).x + (v).y) + ((v).z + (v).w))

// load chunks K, K+1 into named u32x4 VAR (packed bf16), accumulate fp32 sum
#define LOADK(K, VAR) do {                                   \
    f32x4 a_ = xp[(K) * THREADS + tid];                      \
    f32x4 b_ = xp[((K) + 1) * THREADS + tid];                \
    acc += SUM4(a_) + SUM4(b_);                              \
    VAR.x = pack2(a_.x, a_.y); VAR.y = pack2(a_.z, a_.w);    \
    VAR.z = pack2(b_.x, b_.y); VAR.w = pack2(b_.z, b_.w);    \
} while (0)

#define STOREK(K, VAR) do {                                                               \
    __builtin_nontemporal_store(unpack4(VAR.x, VAR.y, s), &op[(K) * THREADS + tid]);      \
    __builtin_nontemporal_store(unpack4(VAR.z, VAR.w, s), &op[((K) + 1) * THREADS + tid]); \
} while (0)

__global__ __launch_bounds__(THREADS, 2) void se_fused(
        const float* __restrict__ x, const float* __restrict__ w1,
        const float* __restrict__ w2, float* __restrict__ out,
        float* __restrict__ sums) {
    __shared__ unsigned uhold[K_LDS * 2 * THREADS];  // 61440 B
    __shared__ float red[8];
    __shared__ float hsh[32];
    __shared__ float scsh;

    const int bid = blockIdx.x;
    const int tid = threadIdx.x;
    const f32x4* xp = (const f32x4*)x + (size_t)bid * (SLICE / 4);  // 65536 f32x4/block

    // ---------------- phase 1: read once, sum, retain ----------------
    float acc = 0.0f;
    u32x4 H00,H01,H02,H03,H04,H05,H06,H07,H08,H09,H10,H11,H12,H13,H14,H15,
          H16,H17,H18,H19,H20,H21,H22,H23,H24,H25,H26,H27,H28,H29,H30,H31;
    LOADK( 0,H00); LOADK( 2,H01); LOADK( 4,H02); LOADK( 6,H03);
    LOADK( 8,H04); LOADK(10,H05); LOADK(12,H06); LOADK(14,H07);
    LOADK(16,H08); LOADK(18,H09); LOADK(20,H10); LOADK(22,H11);
    LOADK(24,H12); LOADK(26,H13); LOADK(28,H14); LOADK(30,H15);
    LOADK(32,H16); LOADK(34,H17); LOADK(36,H18); LOADK(38,H19);
    LOADK(40,H20); LOADK(42,H21); LOADK(44,H22); LOADK(46,H23);
    LOADK(48,H24); LOADK(50,H25); LOADK(52,H26); LOADK(54,H27);
    LOADK(56,H28); LOADK(58,H29); LOADK(60,H30); LOADK(62,H31);

#pragma unroll
    for (int k = 0; k < K_LDS; ++k) {
        f32x4 v = xp[(K_REGC + k) * THREADS + tid];
        acc += SUM4(v);
        uhold[(2 * k) * THREADS + tid]     = pack2(v.x, v.y);
        uhold[(2 * k + 1) * THREADS + tid] = pack2(v.z, v.w);
    }
#pragma unroll
    for (int k = K_REGC + K_LDS; k < K_TOTAL; ++k) {
        f32x4 v = xp[k * THREADS + tid];
        acc += SUM4(v);
    }

    // fixed-order block reduction (deterministic)
    for (int off = 32; off > 0; off >>= 1)
        acc += __shfl_down(acc, off, 64);
    if ((tid & 63) == 0) red[tid >> 6] = acc;
    __syncthreads();
    if (tid == 0) {
        float s0 = 0.0f;
#pragma unroll
        for (int w = 0; w < 8; ++w) s0 += red[w];
        sums[bid] = s0;
    }
    __threadfence();

    // ---------------- grid-wide sync ----------------
    cooperative_groups::this_grid().sync();

    // ---------------- phase 2: tiny MLP, redundant per block ----------------
    const int b = bid & 7, tself = bid >> 3;
    if (tid < 32) {
        float a = 0.0f;
#pragma unroll
        for (int t = 0; t < 32; ++t)
            a += (sums[t * 8 + b] * (1.0f / (float)SLICE)) * w1[tid * 32 + t];
        hsh[tid] = fmaxf(a, 0.0f);
    }
    __syncthreads();
    if (tid == 0) {
        float vv = 0.0f;
#pragma unroll
        for (int j = 0; j < 32; ++j) vv += hsh[j] * w2[tself * 32 + j];
        scsh = 1.0f / (1.0f + expf(-vv));
    }
    __syncthreads();
    const float s = scsh;

    // ---------------- phase 3: re-read tail FIRST (L3-warm), then LDS, regs --
    f32x4* op = (f32x4*)out + (size_t)bid * (SLICE / 4);
#pragma unroll
    for (int k = K_REGC + K_LDS; k < K_TOTAL; ++k) {
        f32x4 v = xp[k * THREADS + tid];
        v *= s;
        __builtin_nontemporal_store(v, &op[k * THREADS + tid]);
    }
#pragma unroll
    for (int k = 0; k < K_LDS; ++k) {
        unsigned lo = uhold[(2 * k) * THREADS + tid];
        unsigned hi = uhold[(2 * k + 1) * THREADS + tid];
        __builtin_nontemporal_store(unpack4(lo, hi, s), &op[(K_REGC + k) * THREADS + tid]);
    }
    STOREK( 0,H00); STOREK( 2,H01); STOREK( 4,H02); STOREK( 6,H03);
    STOREK( 8,H04); STOREK(10,H05); STOREK(12,H06); STOREK(14,H07);
    STOREK(16,H08); STOREK(18,H09); STOREK(20,H10); STOREK(22,H11);
    STOREK(24,H12); STOREK(26,H13); STOREK(28,H14); STOREK(30,H15);
    STOREK(32,H16); STOREK(34,H17); STOREK(36,H18); STOREK(38,H19);
    STOREK(40,H20); STOREK(42,H21); STOREK(44,H22); STOREK(46,H23);
    STOREK(48,H24); STOREK(50,H25); STOREK(52,H26); STOREK(54,H27);
    STOREK(56,H28); STOREK(58,H29); STOREK(60,H30); STOREK(62,H31);
}

extern "C" void kernel_launch(void* const* d_in, const int* in_sizes, int n_in,
                              void* d_out, int out_size, void* d_ws, size_t ws_size,
                              hipStream_t stream) {
    const float* x  = (const float*)d_in[0];
    const float* w1 = (const float*)d_in[1];
    const float* w2 = (const float*)d_in[2];
    float* out  = (float*)d_out;
    float* sums = (float*)d_ws;  // 256 floats

    void* args[] = {(void*)&x, (void*)&w1, (void*)&w2, (void*)&out, (void*)&sums};
    hipLaunchCooperativeKernel((const void*)se_fused, dim3(TBCNT), dim3(THREADS),
                               args, 0, stream);
}

// Round 8
// 188.425 us; speedup vs baseline: 1.5475x; 1.5475x over previous
//
#include <hip/hip_runtime.h>
#include <math.h>

// Geometry (fixed): x (T=32, B=8, C=64, H=64, W=64) fp32 contiguous.
// SLICE = 262144 floats per (t,b) slice; TB = 256 slices; 256 MiB total.
#define SLICE 262144
#define TBCNT 256
#define NPART 8
#define SUMBLOCKS (TBCNT * NPART)   // 2048

typedef float f32x4 __attribute__((ext_vector_type(4)));

// ---------------------------------------------------------------------------
// Kernel A: partial sums (2048 blocks x 256 threads, 8 blocks/CU) + the tiny
// excite MLP executed by whichever block increments the done-counter last.
// Deterministic: partials are written in fixed per-block order, and the
// finalize math is fixed-order regardless of WHICH block runs it.
// ---------------------------------------------------------------------------
__global__ __launch_bounds__(256) void se_sum_kernel(const float* __restrict__ x,
                                                     const float* __restrict__ w1,
                                                     const float* __restrict__ w2,
                                                     float* __restrict__ partial,
                                                     float* __restrict__ scale,
                                                     int* __restrict__ counter) {
    const int bid = blockIdx.x;
    const int tid = threadIdx.x;
    const f32x4* xp = (const f32x4*)x + (size_t)bid * 8192;  // 8192 f32x4 / block

    float acc = 0.0f;
#pragma unroll
    for (int k = 0; k < 32; ++k) {
        f32x4 v = xp[tid + k * 256];
        acc += (v.x + v.y) + (v.z + v.w);
    }

    for (int off = 32; off > 0; off >>= 1)
        acc += __shfl_down(acc, off, 64);

    __shared__ float lds[4];
    if ((tid & 63) == 0) lds[tid >> 6] = acc;
    __syncthreads();

    __shared__ int is_last;
    if (tid == 0) {
        partial[bid] = (lds[0] + lds[1]) + (lds[2] + lds[3]);
        __threadfence();                       // partial visible before counter bump
        int old = atomicAdd(counter, 1);       // device-scope
        is_last = (old == SUMBLOCKS - 1);
    }
    __syncthreads();
    if (!is_last) return;

    // ---- last block: all 2048 partials are globally visible; run the MLP ----
    __shared__ float smean[TBCNT];  // [t*8+b]
    __shared__ float h[8][32];      // [b][j]
    __threadfence();
    float s = 0.0f;
#pragma unroll
    for (int k = 0; k < NPART; ++k) s += partial[tid * NPART + k];
    smean[tid] = s * (1.0f / (float)SLICE);
    __syncthreads();

    const int b = tid >> 5;
    const int j = tid & 31;
    float a = 0.0f;
#pragma unroll
    for (int t = 0; t < 32; ++t) a += smean[t * 8 + b] * w1[j * 32 + t];
    h[b][j] = fmaxf(a, 0.0f);
    __syncthreads();

    const int t = tid & 31;
    float v = 0.0f;
#pragma unroll
    for (int jj = 0; jj < 32; ++jj) v += h[b][jj] * w2[t * 32 + jj];
    scale[t * 8 + b] = 1.0f / (1.0f + expf(-v));
}

// ---------------------------------------------------------------------------
// Kernel B: out = scale[t,b] * x. 2 f32x4 per thread, nt-stores.
// Block covers 2048 contiguous floats -> slice index uniform per block.
// ---------------------------------------------------------------------------
__global__ __launch_bounds__(256) void se_scale_kernel(const float* __restrict__ x,
                                                       const float* __restrict__ scale,
                                                       float* __restrict__ out) {
    const size_t base = (size_t)blockIdx.x * 512;   // f32x4 index
    const int tb = (int)(base >> 16);               // (base*4) >> 18
    const float s = scale[tb];
    const f32x4* xp = (const f32x4*)x;
    f32x4* op = (f32x4*)out;

    size_t i = base + threadIdx.x;
    f32x4 v = xp[i];
    v *= s;
    __builtin_nontemporal_store(v, &op[i]);

    size_t j = i + 256;
    f32x4 u = xp[j];
    u *= s;
    __builtin_nontemporal_store(u, &op[j]);
}

extern "C" void kernel_launch(void* const* d_in, const int* in_sizes, int n_in,
                              void* d_out, int out_size, void* d_ws, size_t ws_size,
                              hipStream_t stream) {
    const float* x  = (const float*)d_in[0];
    const float* w1 = (const float*)d_in[1];
    const float* w2 = (const float*)d_in[2];
    float* out = (float*)d_out;

    int*   counter    = (int*)d_ws;                   // 1 int (aligned region)
    float* ws_partial = (float*)d_ws + 64;            // 2048 floats
    float* ws_scale   = ws_partial + SUMBLOCKS;       // 256 floats

    hipMemsetAsync(counter, 0, sizeof(int), stream);  // graph-capturable, per-launch

    se_sum_kernel<<<SUMBLOCKS, 256, 0, stream>>>(x, w1, w2, ws_partial, ws_scale, counter);

    const size_t total4 = (size_t)TBCNT * SLICE / 4;  // 16,777,216 f32x4
    se_scale_kernel<<<(int)(total4 / 512), 256, 0, stream>>>(x, ws_scale, out);
}

// Round 9
// 118.291 us; speedup vs baseline: 2.4651x; 1.5929x over previous
//
#include <hip/hip_runtime.h>
#include <math.h>

// Geometry (fixed): x (T=32, B=8, C=64, H=64, W=64) fp32 contiguous.
// SLICE = 262144 floats per (t,b) slice; TB = 256 slices; 256 MiB total.
#define SLICE 262144
#define TBCNT 256
#define NPART 8
#define SUMBLOCKS (TBCNT * NPART)   // 2048

typedef float f32x4 __attribute__((ext_vector_type(4)));

// ---------------------------------------------------------------------------
// Kernel A: partial sums. 2048 blocks x 256 threads (8 blocks/CU).
// Block i covers chunk (i & 7) of slice (i >> 3): 32768 contiguous floats.
// No fences/atomics — the kernel boundary publishes `partial` to kernel B.
// ---------------------------------------------------------------------------
__global__ __launch_bounds__(256) void se_sum_kernel(const float* __restrict__ x,
                                                     float* __restrict__ partial) {
    const int bid = blockIdx.x;
    const int tid = threadIdx.x;
    const f32x4* xp = (const f32x4*)x + (size_t)bid * 8192;  // 8192 f32x4 / block

    float acc = 0.0f;
#pragma unroll
    for (int k = 0; k < 32; ++k) {
        f32x4 v = xp[tid + k * 256];
        acc += (v.x + v.y) + (v.z + v.w);
    }

    for (int off = 32; off > 0; off >>= 1)
        acc += __shfl_down(acc, off, 64);

    __shared__ float lds[4];
    if ((tid & 63) == 0) lds[tid >> 6] = acc;
    __syncthreads();
    if (tid == 0) partial[bid] = (lds[0] + lds[1]) + (lds[2] + lds[3]);
}

// ---------------------------------------------------------------------------
// Kernel B: per-block redundant MLP prologue (wave 0, lanes 0..31; all data
// L2/L3-hot) then out = s * x with 2 f32x4/thread and nt-stores.
//   lane t: m[t] = (sum_{c=0..7} partial[(t*8+b)*8+c]) / SLICE
//   lane j: h[j] = relu(sum_t m[t] * w1[j*32+t])        (via __shfl broadcast)
//   s      = sigmoid(sum_j h[j] * w2[tself*32+j])       (butterfly reduce)
// Deterministic: fixed-order sums, fixed butterfly. ~2 KFLOP + ~5.4 KB hot
// reads per block, hidden under the 7 other co-resident blocks' streaming.
// ---------------------------------------------------------------------------
__global__ __launch_bounds__(256) void se_scale_kernel(const float* __restrict__ x,
                                                       const float* __restrict__ w1,
                                                       const float* __restrict__ w2,
                                                       const float* __restrict__ partial,
                                                       float* __restrict__ out) {
    const size_t base = (size_t)blockIdx.x * 512;   // f32x4 index
    const int tb = (int)(base >> 16);               // slice = (base*4) >> 18
    const int b = tb & 7, tself = tb >> 3;
    const int tid = threadIdx.x;

    __shared__ float s_sh;
    if (tid < 32) {
        // m for time index t = lane
        float m = 0.0f;
#pragma unroll
        for (int c = 0; c < NPART; ++c) m += partial[(tid * 8 + b) * NPART + c];
        m *= (1.0f / (float)SLICE);

        // h[j], j = lane: needs all m[t] -> wave shuffle broadcast
        float h = 0.0f;
#pragma unroll
        for (int t = 0; t < 32; ++t) h += __shfl(m, t, 64) * w1[tid * 32 + t];
        h = fmaxf(h, 0.0f);

        // dot(h, w2[tself,:]) via 32-lane butterfly (lanes 0..31 only)
        float v = h * w2[tself * 32 + tid];
#pragma unroll
        for (int off = 16; off > 0; off >>= 1) v += __shfl_xor(v, off, 64);

        if (tid == 0) s_sh = 1.0f / (1.0f + expf(-v));
    }
    __syncthreads();
    const float s = s_sh;

    const f32x4* xp = (const f32x4*)x;
    f32x4* op = (f32x4*)out;

    size_t i = base + tid;
    f32x4 v0 = xp[i];
    v0 *= s;
    __builtin_nontemporal_store(v0, &op[i]);

    size_t j = i + 256;
    f32x4 v1 = xp[j];
    v1 *= s;
    __builtin_nontemporal_store(v1, &op[j]);
}

extern "C" void kernel_launch(void* const* d_in, const int* in_sizes, int n_in,
                              void* d_out, int out_size, void* d_ws, size_t ws_size,
                              hipStream_t stream) {
    const float* x  = (const float*)d_in[0];
    const float* w1 = (const float*)d_in[1];
    const float* w2 = (const float*)d_in[2];
    float* out = (float*)d_out;

    float* ws_partial = (float*)d_ws;   // 2048 floats

    se_sum_kernel<<<SUMBLOCKS, 256, 0, stream>>>(x, ws_partial);

    const size_t total4 = (size_t)TBCNT * SLICE / 4;  // 16,777,216 f32x4
    se_scale_kernel<<<(int)(total4 / 512), 256, 0, stream>>>(x, w1, w2, ws_partial, out);
}